// Round 15
// baseline (51.042 us; speedup 1.0000x reference)
//
#include <hip/hip_runtime.h>
#include <hip/hip_bf16.h>

#define HH 512
#define WW 512
#define HWSZ (512*512)

typedef _Float16 hh4 __attribute__((ext_vector_type(4)));
typedef _Float16 hh2 __attribute__((ext_vector_type(2)));
typedef float    ff4 __attribute__((ext_vector_type(4)));

constexpr int TW = 64, TH = 16;   // output tile
constexpr int SW = 88;            // staged cols bx0-12 .. bx0+75
constexpr int SH = 36;            // staged rows by0-10 .. by0+25
constexpr int LP = 92;            // stride %4==0 (b64 quads + b128 pairs aligned)
constexpr int NG = SW / 4;        // 22 groups of 4 px
constexpr int NSLOT = SH * NG;    // 792
constexpr int NIT = 4;            // 4*256 >= 792 (tail clamped)

__device__ __forceinline__ float clamp01(float x) {
    return __builtin_amdgcn_fmed3f(x, 0.0f, 1.0f);
}
__device__ __forceinline__ hh2 clamp01h2(hh2 x) {
    const hh2 z = {(_Float16)0.0f, (_Float16)0.0f};
    const hh2 o = {(_Float16)1.0f, (_Float16)1.0f};
    return __builtin_elementwise_min(__builtin_elementwise_max(x, z), o);
}
__device__ __forceinline__ hh2 pkrtz(float a, float b) {
    return __builtin_bit_cast(hh2, __builtin_amdgcn_cvt_pkrtz(a, b));
}

__global__ __launch_bounds__(256, 2)
void mlr_fused_kernel(const float* __restrict__ rgbad,
                      const float* __restrict__ lens_eff,
                      const float* __restrict__ focal,
                      float* __restrict__ out,
                      int nbx, int B)
{
    __shared__ uint2 sP[SH * LP];       // half4 {r*pa,g*pa,b*pa,pa}  26.5 KB
    __shared__ uint  rP[SH * LP / 2];   // half2 rp05 pairs            6.6 KB
    __shared__ int   maxbits;

    const int tx  = threadIdx.x;    // 0..15 (4 px each)
    const int ty  = threadIdx.y;    // 0..15
    const int tid = ty * 16 + tx;
    const int bid = blockIdx.x;     // batch-interleaved 1D grid
    const int bb  = bid % B;
    const int t   = bid / B;
    const int bx0 = (t % nbx) * TW;
    const int by0 = (t / nbx) * TH;
    const float lens = lens_eff[bb];
    const int wty0 = ty & ~3;       // wave's base output row (wave-uniform)

    static constexpr float DJ[44] = {
        0.f, 1.f, 1.41421356f, 2.f, 2.23606798f, 2.82842712f, 3.f, 3.16227766f,
        3.60555128f, 4.f, 4.12310563f, 4.24264069f, 4.47213595f, 5.f, 5.09901951f,
        5.38516481f, 5.65685425f, 5.83095189f, 6.f, 6.08276253f, 6.32455532f,
        6.40312424f, 6.70820393f, 7.f, 7.07106781f, 7.21110255f, 7.28010989f,
        7.61577311f, 7.81024968f, 8.f, 8.06225775f, 8.24621125f, 8.48528137f,
        8.54400375f, 8.60232527f, 8.94427191f, 9.f, 9.05538514f, 9.21954446f,
        9.43398113f, 9.48683298f, 9.84885780f, 9.89949494f, 10.f };
    static constexpr float CNT[44] = {
        1,4,4,4,8,4,4,8,8,4,8,4,8,12,8,8,4,8,4,8,8,8,
        8,4,12,8,8,8,8,4,16,8,4,8,8,8,4,8,16,8,8,8,4,12 };

    float blurR[4] = {0,0,0,0}, blurG[4] = {0,0,0,0}, blurB[4] = {0,0,0,0};
    float trans[4] = {1,1,1,1};

#pragma unroll 1
    for (int l = 0; l < 3; ++l) {
        __syncthreads();                 // previous layer fully consumed
        if (tid == 0) maxbits = 0;
        __syncthreads();

        const float* pin = rgbad + (size_t)(bb * 15 + 5 * l) * HWSZ;
        const float* pfo = focal + (size_t)(bb * 15 + 5 * l) * HWSZ;
        float mloc = 0.f;

        // ---- staging: fixed-trip loop, float4 loads (tail clamped, benign) ----
#pragma unroll
        for (int it = 0; it < NIT; ++it) {
            int s = tid + it * 256;
            s = (s < NSLOT) ? s : (NSLOT - 1);
            const int row = s / NG;
            const int grp = s - row * NG;
            const int gy  = by0 - 10 + row;
            const int gx0 = bx0 - 12 + 4 * grp;     // %4 == 0

            ff4 i0 = {0,0,0,0}, i1 = {0,0,0,0}, i2 = {0,0,0,0}, i3 = {0,0,0,0}, i4 = {0,0,0,0};
            ff4 f0 = {0,0,0,0}, f1 = {0,0,0,0}, f2 = {0,0,0,0}, f3 = {0,0,0,0}, f4 = {0,0,0,0};
            const bool valid = ((unsigned)gy < (unsigned)HH) && ((unsigned)gx0 < (unsigned)WW);
            if (valid) {
                const size_t off = (size_t)gy * WW + (size_t)gx0;
                i0 = *reinterpret_cast<const ff4*>(pin + off);
                i1 = *reinterpret_cast<const ff4*>(pin + off +   HWSZ);
                i2 = *reinterpret_cast<const ff4*>(pin + off + 2*HWSZ);
                i3 = *reinterpret_cast<const ff4*>(pin + off + 3*HWSZ);
                i4 = *reinterpret_cast<const ff4*>(pin + off + 4*HWSZ);
                f0 = *reinterpret_cast<const ff4*>(pfo + off);
                f1 = *reinterpret_cast<const ff4*>(pfo + off +   HWSZ);
                f2 = *reinterpret_cast<const ff4*>(pfo + off + 2*HWSZ);
                f3 = *reinterpret_cast<const ff4*>(pfo + off + 3*HWSZ);
                f4 = *reinterpret_cast<const ff4*>(pfo + off + 4*HWSZ);
            }
            uint2 pk[4];
            unsigned short rh[4];
#pragma unroll
            for (int k = 0; k < 4; ++k) {
                const float cr = i0[k] - f0[k];
                const float cg = i1[k] - f1[k];
                const float cb = i2[k] - f2[k];
                const float ca = i3[k] - f3[k];
                const float cd = i4[k] - f4[k];
                const float r  = fminf(fabsf(cd) * lens, 10.f);
                const float rp05 = r + 0.5f;
                const hh2 rp2s = pkrtz(rp05, rp05);
                float aacc = 0.f;
#pragma unroll
                for (int j = 0; j < 44; j += 2) {
                    const hh2 dj2 = {(_Float16)DJ[j], (_Float16)DJ[j + 1]};
                    const hh2 c2  = {(_Float16)CNT[j], (_Float16)CNT[j + 1]};
                    const hh2 w2  = clamp01h2(rp2s - dj2);
                    aacc = __builtin_amdgcn_fdot2(w2, c2, aacc, false);
                }
                const float inv = 1.0f / (aacc + 1e-8f);
                const float pa  = ca * inv;          // 0 when OOB (loads were 0)
                hh4 hv;
                hv.x = (_Float16)(cr * pa);
                hv.y = (_Float16)(cg * pa);
                hv.z = (_Float16)(cb * pa);
                hv.w = (_Float16)pa;
                pk[k] = __builtin_bit_cast(uint2, hv);
                rh[k] = __builtin_bit_cast(unsigned short, (_Float16)rp05);
                mloc  = fmaxf(mloc, rp05);           // 0.5 for OOB px: harmless
            }
            const int base = row * LP + 4 * grp;     // %4 == 0
            uint4 s01, s23;
            s01.x = pk[0].x; s01.y = pk[0].y; s01.z = pk[1].x; s01.w = pk[1].y;
            s23.x = pk[2].x; s23.y = pk[2].y; s23.z = pk[3].x; s23.w = pk[3].y;
            *reinterpret_cast<uint4*>(&sP[base])     = s01;
            *reinterpret_cast<uint4*>(&sP[base + 2]) = s23;
            uint2 rr2;
            rr2.x = (uint)rh[0] | ((uint)rh[1] << 16);
            rr2.y = (uint)rh[2] | ((uint)rh[3] << 16);
            *reinterpret_cast<uint2*>(&rP[base >> 1]) = rr2;
        }
        atomicMax(&maxbits, __float_as_int(mloc));   // positive floats: int max ok
        __syncthreads();

        const float rmax = __int_as_float(maxbits);  // block-uniform (max rp05)
        const int U = min(10, (int)ceilf(rmax) - 1);

        float accR[4] = {0,0,0,0}, accG[4] = {0,0,0,0};
        float accB[4] = {0,0,0,0}, accW[4] = {0,0,0,0};

#define PCOMP(SP_, RPH_, v0) { \
        const hh2 rp2 = __builtin_bit_cast(hh2, (RPH_)); \
        const hh2 cR = __builtin_bit_cast(hh2, __builtin_amdgcn_perm((SP_).z, (SP_).x, 0x05040100u)); \
        const hh2 cG = __builtin_bit_cast(hh2, __builtin_amdgcn_perm((SP_).z, (SP_).x, 0x07060302u)); \
        const hh2 cB = __builtin_bit_cast(hh2, __builtin_amdgcn_perm((SP_).w, (SP_).y, 0x05040100u)); \
        const hh2 cA = __builtin_bit_cast(hh2, __builtin_amdgcn_perm((SP_).w, (SP_).y, 0x07060302u)); \
        _Pragma("unroll") \
        for (int ox = 0; ox < 4; ++ox) { \
            const hh2 w2 = clamp01h2(rp2 - hdd2[(v0) - ox + 13]); \
            accR[ox] = __builtin_amdgcn_fdot2(cR, w2, accR[ox], false); \
            accG[ox] = __builtin_amdgcn_fdot2(cG, w2, accG[ox], false); \
            accB[ox] = __builtin_amdgcn_fdot2(cB, w2, accB[ox], false); \
            accW[ox] = __builtin_amdgcn_fdot2(cA, w2, accW[ox], false); \
        } }
#define LDQ(nm, off)   const uint2 nm = *reinterpret_cast<const uint2*>(&rP[(rbase + (off)) >> 1]);
#define LD128(nm, off) const uint4 nm = *reinterpret_cast<const uint4*>(&sP[rbase + (off)]);

        // ---- gather over SOURCE rows R: all 64 lanes of a wave read the SAME
        // row (16 unique addrs, 4-way same-address broadcast -> conflict-free).
        // Per-lane u = R - 10 - ty; |u|>10 handled by dd = 3000 -> w = 0. ----
        const int R0 = wty0 + 10 - U;          // first src row any lane can use
        const int R1 = wty0 + 13 + U;          // last  (<= 35 = SH-1)
#pragma unroll 1
        for (int R = R0; R <= R1; ++R) {
            const int u0   = R - 10 - wty0;                       // wave-uniform
            const int umin = max(0, max(u0 - 3, -u0));            // min |u| in wave
            const float vm2 = rmax * rmax - (float)(umin * umin); // dx^2 >= vm2 -> w=0
            const int u    = R - 10 - ty;                         // per-lane
            const float u2f = (float)(u * u);

            hh2 hdd2[26];
#pragma unroll
            for (int m = 0; m < 26; ++m) {
                const int dxa = m - 13, dxb = dxa + 1;
                const float qa = u2f + (float)(dxa * dxa);
                const float qb = u2f + (float)(dxb * dxb);
                const float da = (qa <= 100.0f) ? __builtin_sqrtf(qa) : 3000.0f;
                const float db = (qb <= 100.0f) ? __builtin_sqrtf(qb) : 3000.0f;
                hdd2[m] = pkrtz(da, db);
            }

            const int rbase = R * LP + 12 + 4 * tx;   // SAME for all ty in wave

            LDQ(q_m4, -4) LDQ(q_0, 0) LDQ(q_4, 4)
            LD128(s_m2, -2) LD128(s_0, 0) LD128(s_2, 2) LD128(s_4, 4)
            PCOMP(s_m2, q_m4.y, -2) PCOMP(s_0, q_0.x, 0)
            PCOMP(s_2,  q_0.y,  2) PCOMP(s_4, q_4.x, 4)
            if (vm2 > 9.0f) {
                LDQ(q_m8, -8) LDQ(q_8, 8)
                LD128(s_m6, -6) LD128(s_m4, -4) LD128(s_6, 6) LD128(s_8, 8)
                PCOMP(s_m6, q_m8.y, -6) PCOMP(s_m4, q_m4.x, -4)
                PCOMP(s_6,  q_4.y,  6) PCOMP(s_8,  q_8.x,  8)
                if (vm2 > 36.0f) {
                    LD128(s_m8, -8) LD128(s_10, 10)
                    PCOMP(s_m8, q_m8.x, -8) PCOMP(s_10, q_8.y, 10)
                    if (vm2 > 81.0f) {
                        LDQ(q_m12, -12) LDQ(q_12, 12)
                        LD128(s_m10, -10) LD128(s_12, 12)
                        PCOMP(s_m10, q_m12.y, -10) PCOMP(s_12, q_12.x, 12)
                    }
                }
            }
        }
#undef PCOMP
#undef LDQ
#undef LD128

        // front-to-back compositing (trans=1 at l=0)
#pragma unroll
        for (int ox = 0; ox < 4; ++ox) {
            const float wsum = accW[ox];
            const float occ  = clamp01(wsum);
            const float f    = trans[ox] * occ / (wsum + 1e-8f);
            blurR[ox] = fmaf(accR[ox], f, blurR[ox]);
            blurG[ox] = fmaf(accG[ox], f, blurG[ox]);
            blurB[ox] = fmaf(accB[ox], f, blurB[ox]);
            trans[ox] *= (1.0f - occ);
        }
    }

    const int oy = by0 + ty;
    const size_t obase = (size_t)bb * 3 * HWSZ + (size_t)oy * WW + (size_t)(bx0 + 4 * tx);

    float4 vR, vG, vB;
    vR.x = blurR[0]; vR.y = blurR[1]; vR.z = blurR[2]; vR.w = blurR[3];
    vG.x = blurG[0]; vG.y = blurG[1]; vG.z = blurG[2]; vG.w = blurG[3];
    vB.x = blurB[0]; vB.y = blurB[1]; vB.z = blurB[2]; vB.w = blurB[3];

    *reinterpret_cast<float4*>(out + obase)            = vR;
    *reinterpret_cast<float4*>(out + obase + HWSZ)     = vG;
    *reinterpret_cast<float4*>(out + obase + 2 * HWSZ) = vB;
}

extern "C" void kernel_launch(void* const* d_in, const int* in_sizes, int n_in,
                              void* d_out, int out_size, void* d_ws, size_t ws_size,
                              hipStream_t stream) {
    const float* rgbad = (const float*)d_in[0];
    const float* lens  = (const float*)d_in[1];
    const float* focal = (const float*)d_in[2];
    float* out = (float*)d_out;
    const int B = in_sizes[1];                 // lens_effect: [B,1]
    const int nbx = WW / TW;                   // 8
    const int nby = HH / TH;                   // 32
    dim3 grid(nbx * nby * B, 1, 1);            // 1D, batch-interleaved
    dim3 block(16, 16, 1);
    hipLaunchKernelGGL(mlr_fused_kernel, grid, block, 0, stream,
                       rgbad, lens, focal, out, nbx, B);
}

// Round 16
// 42.006 us; speedup vs baseline: 1.2151x; 1.2151x over previous
//
#include <hip/hip_runtime.h>
#include <hip/hip_bf16.h>

#define HH 512
#define WW 512
#define HWSZ (512*512)

typedef _Float16 hh4 __attribute__((ext_vector_type(4)));
typedef _Float16 hh2 __attribute__((ext_vector_type(2)));
typedef float    ff4 __attribute__((ext_vector_type(4)));

constexpr int TW = 64, TH = 16;
constexpr int SW = 88;          // staged cols bx0-12 .. bx0+75
constexpr int SH = TH + 20;     // 36 rows
constexpr int LP = 92;          // stride %4==0: b64 rp quads + b128 pairs aligned
constexpr int NG = SW / 4;      // 22 groups of 4 px per row
constexpr int NSLOT = SH * NG;  // 792

__device__ __forceinline__ float clamp01(float x) {
    return __builtin_amdgcn_fmed3f(x, 0.0f, 1.0f);
}
__device__ __forceinline__ hh2 clamp01h2(hh2 x) {
    const hh2 z = {(_Float16)0.0f, (_Float16)0.0f};
    const hh2 o = {(_Float16)1.0f, (_Float16)1.0f};
    return __builtin_elementwise_min(__builtin_elementwise_max(x, z), o);
}
__device__ __forceinline__ hh2 pkrtz(float a, float b) {
    return __builtin_bit_cast(hh2, __builtin_amdgcn_cvt_pkrtz(a, b));
}

// two staging slot-iterations' worth of raw loads (held in VGPRs)
struct StageRegs { ff4 v[2][10]; };   // [slot][i0..i4,f0..f4]

__device__ __forceinline__ StageRegs stage_issue(const float* __restrict__ pin,
                                                 const float* __restrict__ pfo,
                                                 int tid, int bx0, int by0, int itBase) {
    StageRegs R;
#pragma unroll
    for (int k = 0; k < 2; ++k) {
        int s = tid + (itBase + k) * 256;
        s = (s < NSLOT) ? s : (NSLOT - 1);
        const int row = s / NG;
        const int grp = s - row * NG;
        const int gy  = by0 - 10 + row;
        const int gx0 = bx0 - 12 + 4 * grp;
        const ff4 z = {0, 0, 0, 0};
#pragma unroll
        for (int c = 0; c < 10; ++c) R.v[k][c] = z;
        if (((unsigned)gy < (unsigned)HH) && ((unsigned)gx0 < (unsigned)WW)) {
            const size_t off = (size_t)gy * WW + (size_t)gx0;
#pragma unroll
            for (int c = 0; c < 5; ++c)
                R.v[k][c] = *reinterpret_cast<const ff4*>(pin + off + (size_t)c * HWSZ);
#pragma unroll
            for (int c = 0; c < 5; ++c)
                R.v[k][5 + c] = *reinterpret_cast<const ff4*>(pfo + off + (size_t)c * HWSZ);
        }
    }
    return R;
}

__device__ __forceinline__ void stage_commit(const StageRegs& R, float lens,
                                             int tid, int itBase,
                                             uint2* __restrict__ sPb, uint* __restrict__ rPb,
                                             float& mloc) {
    static constexpr float DJ[44] = {
        0.f, 1.f, 1.41421356f, 2.f, 2.23606798f, 2.82842712f, 3.f, 3.16227766f,
        3.60555128f, 4.f, 4.12310563f, 4.24264069f, 4.47213595f, 5.f, 5.09901951f,
        5.38516481f, 5.65685425f, 5.83095189f, 6.f, 6.08276253f, 6.32455532f,
        6.40312424f, 6.70820393f, 7.f, 7.07106781f, 7.21110255f, 7.28010989f,
        7.61577311f, 7.81024968f, 8.f, 8.06225775f, 8.24621125f, 8.48528137f,
        8.54400375f, 8.60232527f, 8.94427191f, 9.f, 9.05538514f, 9.21954446f,
        9.43398113f, 9.48683298f, 9.84885780f, 9.89949494f, 10.f };
    static constexpr float CNT[44] = {
        1,4,4,4,8,4,4,8,8,4,8,4,8,12,8,8,4,8,4,8,8,8,
        8,4,12,8,8,8,8,4,16,8,4,8,8,8,4,8,16,8,8,8,4,12 };

#pragma unroll
    for (int k = 0; k < 2; ++k) {
        int s = tid + (itBase + k) * 256;
        s = (s < NSLOT) ? s : (NSLOT - 1);
        const int row = s / NG;
        const int grp = s - row * NG;
        uint2 pk[4];
        unsigned short rh[4];
#pragma unroll
        for (int j = 0; j < 4; ++j) {
            const float cr = R.v[k][0][j] - R.v[k][5][j];
            const float cg = R.v[k][1][j] - R.v[k][6][j];
            const float cb = R.v[k][2][j] - R.v[k][7][j];
            const float ca = R.v[k][3][j] - R.v[k][8][j];
            const float cd = R.v[k][4][j] - R.v[k][9][j];
            const float r  = fminf(fabsf(cd) * lens, 10.f);
            const float rp05 = r + 0.5f;
            const hh2 rp2s = pkrtz(rp05, rp05);
            float aacc = 0.f;
#pragma unroll
            for (int j2 = 0; j2 < 44; j2 += 2) {
                const hh2 dj2 = {(_Float16)DJ[j2], (_Float16)DJ[j2 + 1]};
                const hh2 c2  = {(_Float16)CNT[j2], (_Float16)CNT[j2 + 1]};
                const hh2 w2  = clamp01h2(rp2s - dj2);
                aacc = __builtin_amdgcn_fdot2(w2, c2, aacc, false);
            }
            const float inv = 1.0f / (aacc + 1e-8f);
            const float pa  = ca * inv;          // 0 when OOB (loads were 0)
            hh4 hv;
            hv.x = (_Float16)(cr * pa);
            hv.y = (_Float16)(cg * pa);
            hv.z = (_Float16)(cb * pa);
            hv.w = (_Float16)pa;
            pk[j] = __builtin_bit_cast(uint2, hv);
            rh[j] = __builtin_bit_cast(unsigned short, (_Float16)rp05);
            mloc  = fmaxf(mloc, rp05);           // 0.5 for OOB px: harmless
        }
        const int base = row * LP + 4 * grp;     // %4 == 0
        uint4 s01, s23;
        s01.x = pk[0].x; s01.y = pk[0].y; s01.z = pk[1].x; s01.w = pk[1].y;
        s23.x = pk[2].x; s23.y = pk[2].y; s23.z = pk[3].x; s23.w = pk[3].y;
        *reinterpret_cast<uint4*>(&sPb[base])     = s01;
        *reinterpret_cast<uint4*>(&sPb[base + 2]) = s23;
        uint2 rr2;
        rr2.x = (uint)rh[0] | ((uint)rh[1] << 16);
        rr2.y = (uint)rh[2] | ((uint)rh[3] << 16);
        *reinterpret_cast<uint2*>(&rPb[base >> 1]) = rr2;
    }
}

__global__ __launch_bounds__(256, 2)
void mlr_fused_kernel(const float* __restrict__ rgbad,
                      const float* __restrict__ lens_eff,
                      const float* __restrict__ focal,
                      float* __restrict__ out,
                      int nbx, int B)
{
    __shared__ uint2 sP[2][SH * LP];       // 2 x 25.9 KB half4 planes
    __shared__ uint  rP[2][SH * LP / 2];   // 2 x  6.5 KB half2 rp planes
    __shared__ int   mb[3];

    const int tx  = threadIdx.x;    // 0..15 (4 px each)
    const int ty  = threadIdx.y;    // 0..15
    const int tid = ty * 16 + tx;
    const int bid = blockIdx.x;     // batch-interleaved 1D grid
    const int bb  = bid % B;
    const int t   = bid / B;
    const int bx0 = (t % nbx) * TW;
    const int by0 = (t / nbx) * TH;
    const float lens = lens_eff[bb];

    if (tid < 3) mb[tid] = 0;
    __syncthreads();

    float blurR[4] = {0,0,0,0}, blurG[4] = {0,0,0,0}, blurB[4] = {0,0,0,0};
    float trans[4] = {1,1,1,1};

    // ---- prologue: stage layer 0 into buffer 0 ----
    {
        const float* pin = rgbad + (size_t)(bb * 15) * HWSZ;
        const float* pfo = focal + (size_t)(bb * 15) * HWSZ;
        StageRegs a = stage_issue(pin, pfo, tid, bx0, by0, 0);
        StageRegs b = stage_issue(pin, pfo, tid, bx0, by0, 2);
        float mloc = 0.f;
        stage_commit(a, lens, tid, 0, sP[0], rP[0], mloc);
        stage_commit(b, lens, tid, 2, sP[0], rP[0], mloc);
        atomicMax(&mb[0], __float_as_int(mloc));
    }
    __syncthreads();

#pragma unroll 1
    for (int l = 0; l < 3; ++l) {
        const int cur = l & 1;
        const float rmax = __int_as_float(mb[l]);        // block-uniform
        const int U = min(10, (int)ceilf(rmax) - 1);

        uint2* const sPc = sP[cur];
        uint*  const rPc = rP[cur];

        // issue first half of next layer's staging loads (latency hides under gather)
        const float* pinN = rgbad + (size_t)(bb * 15 + 5 * (l + 1)) * HWSZ;
        const float* pfoN = focal + (size_t)(bb * 15 + 5 * (l + 1)) * HWSZ;
        StageRegs pre;
        if (l < 2) pre = stage_issue(pinN, pfoN, tid, bx0, by0, 0);

        float accR[4] = {0,0,0,0}, accG[4] = {0,0,0,0};
        float accB[4] = {0,0,0,0}, accW[4] = {0,0,0,0};

        // one pair (2 source cols) applied to the 4 output px
#define PCOMP(SP_, RPH_, v0) { \
            const hh2 rp2 = __builtin_bit_cast(hh2, (RPH_)); \
            const hh2 cR = __builtin_bit_cast(hh2, __builtin_amdgcn_perm((SP_).z, (SP_).x, 0x05040100u)); \
            const hh2 cG = __builtin_bit_cast(hh2, __builtin_amdgcn_perm((SP_).z, (SP_).x, 0x07060302u)); \
            const hh2 cB = __builtin_bit_cast(hh2, __builtin_amdgcn_perm((SP_).w, (SP_).y, 0x05040100u)); \
            const hh2 cA = __builtin_bit_cast(hh2, __builtin_amdgcn_perm((SP_).w, (SP_).y, 0x07060302u)); \
            _Pragma("unroll") \
            for (int ox = 0; ox < 4; ++ox) { \
                const hh2 w2 = clamp01h2(rp2 - hdd2[(v0) - ox + 13]); \
                accR[ox] = __builtin_amdgcn_fdot2(cR, w2, accR[ox], false); \
                accG[ox] = __builtin_amdgcn_fdot2(cG, w2, accG[ox], false); \
                accB[ox] = __builtin_amdgcn_fdot2(cB, w2, accB[ox], false); \
                accW[ox] = __builtin_amdgcn_fdot2(cA, w2, accW[ox], false); \
            } }
#define LDQ(nm, rb, off)  const uint2 nm = *reinterpret_cast<const uint2*>(&rPc[((rb) + (off)) >> 1]);
#define LD128(nm, rb, off) const uint4 nm = *reinterpret_cast<const uint4*>(&sPc[(rb) + (off)]);

        // ---- u = 0 row ----
        {
            hh2 hdd2[26];
#pragma unroll
            for (int m = 0; m < 26; ++m) {
                const int dxa = m - 13, dxb = dxa + 1;
                const float qa = (float)(dxa * dxa);
                const float qb = (float)(dxb * dxb);
                const float da = (qa <= 100.0f) ? __builtin_sqrtf(qa) : 3000.0f;
                const float db = (qb <= 100.0f) ? __builtin_sqrtf(qb) : 3000.0f;
                hdd2[m] = pkrtz(da, db);
            }
            const float vm2 = rmax * rmax;
            const int rbA = (ty + 10) * LP + 12 + 4 * tx;   // %4 == 0
            LDQ(qAm4, rbA, -4) LDQ(qA0, rbA, 0) LDQ(qA4, rbA, 4)
            LD128(sAm2, rbA, -2) LD128(sA0, rbA, 0) LD128(sA2, rbA, 2) LD128(sA4, rbA, 4)
            PCOMP(sAm2, qAm4.y, -2) PCOMP(sA0, qA0.x, 0) PCOMP(sA2, qA0.y, 2) PCOMP(sA4, qA4.x, 4)
            if (vm2 > 9.0f) {
                LDQ(qAm8, rbA, -8) LDQ(qA8, rbA, 8)
                LD128(sAm6, rbA, -6) LD128(sAm4, rbA, -4) LD128(sA6, rbA, 6) LD128(sA8, rbA, 8)
                PCOMP(sAm6, qAm8.y, -6) PCOMP(sAm4, qAm4.x, -4) PCOMP(sA6, qA4.y, 6) PCOMP(sA8, qA8.x, 8)
                if (vm2 > 36.0f) {
                    LD128(sAm8, rbA, -8) LD128(sA10, rbA, 10)
                    PCOMP(sAm8, qAm8.x, -8) PCOMP(sA10, qA8.y, 10)
                    if (vm2 > 81.0f) {
                        LDQ(qAm12, rbA, -12) LDQ(qA12, rbA, 12)
                        LD128(sAm10, rbA, -10) LD128(sA12, rbA, 12)
                        PCOMP(sAm10, qAm12.y, -10) PCOMP(sA12, qA12.x, 12)
                    }
                }
            }
        }

        // ---- u = +/-au row pairs (shared hdd2: d depends on u^2 only) ----
#pragma unroll 1
        for (int au = 1; au <= U; ++au) {
            const float u2f = (float)(au * au);
            const float vm2 = rmax * rmax - u2f;
            hh2 hdd2[26];
#pragma unroll
            for (int m = 0; m < 26; ++m) {
                const int dxa = m - 13, dxb = dxa + 1;
                const float qa = u2f + (float)(dxa * dxa);
                const float qb = u2f + (float)(dxb * dxb);
                const float da = (qa <= 100.0f) ? __builtin_sqrtf(qa) : 3000.0f;
                const float db = (qb <= 100.0f) ? __builtin_sqrtf(qb) : 3000.0f;
                hdd2[m] = pkrtz(da, db);
            }
            const int rbA = (ty + 10 + au) * LP + 12 + 4 * tx;
            const int rbB = (ty + 10 - au) * LP + 12 + 4 * tx;

            LDQ(qAm4, rbA, -4) LDQ(qA0, rbA, 0) LDQ(qA4, rbA, 4)
            LD128(sAm2, rbA, -2) LD128(sA0, rbA, 0) LD128(sA2, rbA, 2) LD128(sA4, rbA, 4)
            LDQ(qBm4, rbB, -4) LDQ(qB0, rbB, 0) LDQ(qB4, rbB, 4)
            LD128(sBm2, rbB, -2) LD128(sB0, rbB, 0) LD128(sB2, rbB, 2) LD128(sB4, rbB, 4)
            PCOMP(sAm2, qAm4.y, -2) PCOMP(sA0, qA0.x, 0) PCOMP(sA2, qA0.y, 2) PCOMP(sA4, qA4.x, 4)
            PCOMP(sBm2, qBm4.y, -2) PCOMP(sB0, qB0.x, 0) PCOMP(sB2, qB0.y, 2) PCOMP(sB4, qB4.x, 4)
            if (vm2 > 9.0f) {
                LDQ(qAm8, rbA, -8) LDQ(qA8, rbA, 8)
                LD128(sAm6, rbA, -6) LD128(sAm4, rbA, -4) LD128(sA6, rbA, 6) LD128(sA8, rbA, 8)
                LDQ(qBm8, rbB, -8) LDQ(qB8, rbB, 8)
                LD128(sBm6, rbB, -6) LD128(sBm4, rbB, -4) LD128(sB6, rbB, 6) LD128(sB8, rbB, 8)
                PCOMP(sAm6, qAm8.y, -6) PCOMP(sAm4, qAm4.x, -4) PCOMP(sA6, qA4.y, 6) PCOMP(sA8, qA8.x, 8)
                PCOMP(sBm6, qBm8.y, -6) PCOMP(sBm4, qBm4.x, -4) PCOMP(sB6, qB4.y, 6) PCOMP(sB8, qB8.x, 8)
                if (vm2 > 36.0f) {
                    LD128(sAm8, rbA, -8) LD128(sA10, rbA, 10)
                    LD128(sBm8, rbB, -8) LD128(sB10, rbB, 10)
                    PCOMP(sAm8, qAm8.x, -8) PCOMP(sA10, qA8.y, 10)
                    PCOMP(sBm8, qBm8.x, -8) PCOMP(sB10, qB8.y, 10)
                    if (vm2 > 81.0f) {
                        LDQ(qAm12, rbA, -12) LDQ(qA12, rbA, 12)
                        LD128(sAm10, rbA, -10) LD128(sA12, rbA, 12)
                        LDQ(qBm12, rbB, -12) LDQ(qB12, rbB, 12)
                        LD128(sBm10, rbB, -10) LD128(sB12, rbB, 12)
                        PCOMP(sAm10, qAm12.y, -10) PCOMP(sA12, qA12.x, 12)
                        PCOMP(sBm10, qBm12.y, -10) PCOMP(sB12, qB12.x, 12)
                    }
                }
            }
        }
#undef PCOMP
#undef LDQ
#undef LD128

        // ---- finish next layer's staging (overlaps 2nd-half load latency) ----
        if (l < 2) {
            StageRegs pre2 = stage_issue(pinN, pfoN, tid, bx0, by0, 2);
            float mloc = 0.f;
            stage_commit(pre,  lens, tid, 0, sP[cur ^ 1], rP[cur ^ 1], mloc);
            stage_commit(pre2, lens, tid, 2, sP[cur ^ 1], rP[cur ^ 1], mloc);
            atomicMax(&mb[l + 1], __float_as_int(mloc));
        }

        // ---- front-to-back compositing ----
#pragma unroll
        for (int ox = 0; ox < 4; ++ox) {
            const float wsum = accW[ox];
            const float occ  = clamp01(wsum);
            const float f    = trans[ox] * occ / (wsum + 1e-8f);
            blurR[ox] = fmaf(accR[ox], f, blurR[ox]);
            blurG[ox] = fmaf(accG[ox], f, blurG[ox]);
            blurB[ox] = fmaf(accB[ox], f, blurB[ox]);
            trans[ox] *= (1.0f - occ);
        }
        __syncthreads();   // staging l+1 done; gather l done -> buffers safe
    }

    const int oy = by0 + ty;
    const size_t obase = (size_t)bb * 3 * HWSZ + (size_t)oy * WW + (size_t)(bx0 + 4 * tx);

    float4 vR, vG, vB;
    vR.x = blurR[0]; vR.y = blurR[1]; vR.z = blurR[2]; vR.w = blurR[3];
    vG.x = blurG[0]; vG.y = blurG[1]; vG.z = blurG[2]; vG.w = blurG[3];
    vB.x = blurB[0]; vB.y = blurB[1]; vB.z = blurB[2]; vB.w = blurB[3];

    *reinterpret_cast<float4*>(out + obase)            = vR;
    *reinterpret_cast<float4*>(out + obase + HWSZ)     = vG;
    *reinterpret_cast<float4*>(out + obase + 2 * HWSZ) = vB;
}

extern "C" void kernel_launch(void* const* d_in, const int* in_sizes, int n_in,
                              void* d_out, int out_size, void* d_ws, size_t ws_size,
                              hipStream_t stream) {
    const float* rgbad = (const float*)d_in[0];
    const float* lens  = (const float*)d_in[1];
    const float* focal = (const float*)d_in[2];
    float* out = (float*)d_out;
    const int B = in_sizes[1];                 // lens_effect: [B,1]
    const int nbx = WW / 64;                   // 8
    const int nby = HH / 16;                   // 32
    dim3 grid(nbx * nby * B, 1, 1);            // 1D, batch-interleaved
    dim3 block(16, 16, 1);
    hipLaunchKernelGGL(mlr_fused_kernel, grid, block, 0, stream,
                       rgbad, lens, focal, out, nbx, B);
}